// Round 1
// baseline (804.883 us; speedup 1.0000x reference)
//
#include <hip/hip_runtime.h>

// LeNet-5 forward, fp32 baseline.
// Layers: conv1 1->10 k10 (28->19), conv2 10->20 k10 (19->10),
//         conv3 20->20 k5 (10->6), fc 720->10.
// Strategy: weights read at wave-uniform addresses -> s_load -> SGPR operand
// of v_fmac (no vector-mem cost for weights). Inputs staged in LDS.

#define C2_IMGS 4
#define C2_THREADS 448   // 7 waves; 400 active compute threads (4 img x 100 pos)
#define C3_IMGS 6
#define C3_THREADS 256   // 216 active compute threads (6 img x 36 pos)

// ---------------- conv1: [B,1,28,28] -> relu -> [B,10,19,19] ----------------
__global__ __launch_bounds__(384) void conv1_k(const float* __restrict__ x,
                                               const float* __restrict__ w1,
                                               const float* __restrict__ b1,
                                               float* __restrict__ h1) {
    __shared__ float sx[784];
    const int b = blockIdx.x;
    const float* xb = x + b * 784;
    for (int k = threadIdx.x; k < 784; k += 384) sx[k] = xb[k];
    __syncthreads();
    const int t = threadIdx.x;
    if (t >= 361) return;
    const int oy = t / 19, ox = t % 19;
    float acc[10];
#pragma unroll
    for (int o = 0; o < 10; ++o) acc[o] = b1[o];
#pragma unroll 1
    for (int i = 0; i < 10; ++i) {
        float r[10];
#pragma unroll
        for (int j = 0; j < 10; ++j) r[j] = sx[(oy + i) * 28 + ox + j];
        const float* wp = w1 + i * 10;   // w1[o][i][j] = wp[o*100 + j]
#pragma unroll
        for (int j = 0; j < 10; ++j) {
#pragma unroll
            for (int o = 0; o < 10; ++o)
                acc[o] += r[j] * wp[o * 100 + j];
        }
    }
    float* outp = h1 + b * 3610 + t;
#pragma unroll
    for (int o = 0; o < 10; ++o) outp[o * 361] = fmaxf(acc[o], 0.f);
}

// ---------------- conv2: [B,10,19,19] -> relu -> [B,20,10,10] ---------------
__global__ __launch_bounds__(C2_THREADS) void conv2_k(const float* __restrict__ h1,
                                                      const float* __restrict__ w2,
                                                      const float* __restrict__ b2,
                                                      float* __restrict__ h2, int B) {
    __shared__ float sin_[C2_IMGS * 3610];   // 57.8 KB
    const int b0 = blockIdx.x * C2_IMGS;
    const int nimg = min(C2_IMGS, B - b0);
    const int tot = nimg * 3610;
    const float* src = h1 + b0 * 3610;
    for (int k = threadIdx.x; k < tot; k += C2_THREADS) sin_[k] = src[k];
    __syncthreads();
    const int t = threadIdx.x;
    const int ii = t / 100, pos = t % 100;
    if (ii >= nimg) return;
    const int oy = pos / 10, ox = pos % 10;
    const float* sb = sin_ + ii * 3610;
    float acc[20];
#pragma unroll
    for (int o = 0; o < 20; ++o) acc[o] = b2[o];
#pragma unroll 1
    for (int c = 0; c < 10; ++c) {
#pragma unroll 1
        for (int i = 0; i < 10; ++i) {
            float r[10];
#pragma unroll
            for (int j = 0; j < 10; ++j)
                r[j] = sb[c * 361 + (oy + i) * 19 + ox + j];
            const float* wp = w2 + c * 100 + i * 10;  // w2[o][c][i][j]=wp[o*1000+j]
#pragma unroll
            for (int j = 0; j < 10; ++j) {
#pragma unroll
                for (int o = 0; o < 20; ++o)
                    acc[o] += r[j] * wp[o * 1000 + j];
            }
        }
    }
    float* outp = h2 + (b0 + ii) * 2000 + pos;
#pragma unroll
    for (int o = 0; o < 20; ++o) outp[o * 100] = fmaxf(acc[o], 0.f);
}

// -------- conv3 + fc fused: [B,20,10,10] -> relu -> [B,720] @ wf^T + bf -----
__global__ __launch_bounds__(C3_THREADS) void conv3fc_k(const float* __restrict__ h2,
                                                        const float* __restrict__ w3,
                                                        const float* __restrict__ b3,
                                                        const float* __restrict__ wf,
                                                        const float* __restrict__ bf,
                                                        float* __restrict__ out, int B) {
    __shared__ float sin_[C3_IMGS * 2000];        // 48 KB
    __shared__ float spart[C3_IMGS * 36 * 10];    // 8.6 KB  fc partials
    const int b0 = blockIdx.x * C3_IMGS;
    const int nimg = min(C3_IMGS, B - b0);
    const int tot = nimg * 2000;
    const float* src = h2 + b0 * 2000;
    for (int k = threadIdx.x; k < tot; k += C3_THREADS) sin_[k] = src[k];
    __syncthreads();
    const int t = threadIdx.x;
    const int ii = t / 36, pos = t % 36;
    if (ii < nimg && t < C3_IMGS * 36) {
        const int oy = pos / 6, ox = pos % 6;
        const float* sb = sin_ + ii * 2000;
        float acc[20];
#pragma unroll
        for (int o = 0; o < 20; ++o) acc[o] = b3[o];
#pragma unroll 1
        for (int c = 0; c < 20; ++c) {
#pragma unroll 1
            for (int i = 0; i < 5; ++i) {
                float r[5];
#pragma unroll
                for (int j = 0; j < 5; ++j)
                    r[j] = sb[c * 100 + (oy + i) * 10 + ox + j];
                const float* wp = w3 + c * 25 + i * 5; // w3[o][c][i][j]=wp[o*500+j]
#pragma unroll
                for (int j = 0; j < 5; ++j) {
#pragma unroll
                    for (int o = 0; o < 20; ++o)
                        acc[o] += r[j] * wp[o * 500 + j];
                }
            }
        }
        // fc partials: h3 element (o,pos) contributes acc_relu * wf[n, o*36+pos]
        float part[10];
#pragma unroll
        for (int n = 0; n < 10; ++n) part[n] = 0.f;
#pragma unroll 1
        for (int o = 0; o < 20; ++o) {
            const float v = fmaxf(acc[o], 0.f);
            const float* wfp = wf + o * 36 + pos;   // wf[n][k]: stride 720 per n
#pragma unroll
            for (int n = 0; n < 10; ++n) part[n] += v * wfp[n * 720];
        }
        float* pp = spart + (ii * 36 + pos) * 10;
#pragma unroll
        for (int n = 0; n < 10; ++n) pp[n] = part[n];
    }
    __syncthreads();
    if (t < nimg * 10) {
        const int fi = t / 10, n = t % 10;
        float s = bf[n];
        const float* pp = spart + fi * 360 + n;
#pragma unroll 4
        for (int p = 0; p < 36; ++p) s += pp[p * 10];
        out[(b0 + fi) * 10 + n] = s;
    }
}

extern "C" void kernel_launch(void* const* d_in, const int* in_sizes, int n_in,
                              void* d_out, int out_size, void* d_ws, size_t ws_size,
                              hipStream_t stream) {
    (void)n_in; (void)out_size; (void)ws_size;
    const float* x  = (const float*)d_in[0];
    const float* w1 = (const float*)d_in[1];
    const float* b1 = (const float*)d_in[2];
    const float* w2 = (const float*)d_in[3];
    const float* b2 = (const float*)d_in[4];
    const float* w3 = (const float*)d_in[5];
    const float* b3 = (const float*)d_in[6];
    const float* wf = (const float*)d_in[7];
    const float* bf = (const float*)d_in[8];
    float* out = (float*)d_out;

    const int B = in_sizes[0] / 784;           // 4096

    float* h1 = (float*)d_ws;                  // B*3610 floats = 59.2 MB
    float* h2 = h1 + (size_t)B * 3610;         // B*2000 floats = 32.8 MB

    conv1_k<<<B, 384, 0, stream>>>(x, w1, b1, h1);
    conv2_k<<<(B + C2_IMGS - 1) / C2_IMGS, C2_THREADS, 0, stream>>>(h1, w2, b2, h2, B);
    conv3fc_k<<<(B + C3_IMGS - 1) / C3_IMGS, C3_THREADS, 0, stream>>>(h2, w3, b3, wf, bf, out, B);
}

// Round 2
// 352.411 us; speedup vs baseline: 2.2839x; 2.2839x over previous
//
#include <hip/hip_runtime.h>

// LeNet-5 forward. conv2 via bf16 MFMA (16x16x32), conv1/conv3/fc fp32 VALU.
// h1 stored bf16 NHWC with C padded to 16 ("C16"): row y = [x*16 + c], row
// length 304 elems (19 x-positions), 21 rows (rows 19,20 zero for M-padding).
// Then conv2's im2col K-slice for fixed kernel-row i is k=(j*16+c), and every
// MFMA A-fragment (8 consecutive k) is one 16B-aligned ds_read_b128.

typedef short s16x8 __attribute__((ext_vector_type(8)));   // 8 bf16 (4 VGPRs)
typedef float f32x4 __attribute__((ext_vector_type(4)));

#define H1_ROW 304            // 19*16
#define H1_IMG 6384           // 21*304 elems (12768 B)
#define C3_IMGS 6
#define C3_THREADS 256

static __device__ __forceinline__ unsigned short f2bf(float f) {
    union { float f; unsigned int u; } v; v.f = f;
    unsigned int u = v.u;
    unsigned int r = (u + 0x7fffu + ((u >> 16) & 1u)) >> 16;   // RNE
    return (unsigned short)r;
}

// ------------- weight prep: w2 [20,10,10,10] -> B-fragment order -----------
// wbuf[i][ck(5)][nt(2)][lane(64)][t(8)] bf16; k = ck*32 + (lane>>4)*8 + t,
// o = nt*16 + (lane&15); j = k/16, c = k%16; val = w2[o][c][i][j] (0 if pad).
__global__ __launch_bounds__(256) void wprep_k(const float* __restrict__ w2,
                                               unsigned short* __restrict__ wbuf) {
    int e = blockIdx.x * 256 + threadIdx.x;      // 0..51199
    if (e >= 51200) return;
    int t    = e & 7;
    int lane = (e >> 3) & 63;
    int nt   = (e >> 9) & 1;
    int ck   = (e >> 10) % 5;
    int i    = e / 5120;
    int k = ck * 32 + (lane >> 4) * 8 + t;       // 0..159
    int o = nt * 16 + (lane & 15);
    int j = k >> 4, c = k & 15;
    float val = (c < 10 && o < 20) ? w2[o * 1000 + c * 100 + i * 10 + j] : 0.f;
    wbuf[e] = f2bf(val);
}

// ---------------- conv1: [B,1,28,28] -> relu -> h1p bf16 NHWC-C16 ----------
__global__ __launch_bounds__(384) void conv1_k(const float* __restrict__ x,
                                               const float* __restrict__ w1,
                                               const float* __restrict__ b1,
                                               unsigned short* __restrict__ h1p) {
    __shared__ float sx[784];
    const int b = blockIdx.x;
    const float* xb = x + b * 784;
    for (int k = threadIdx.x; k < 784; k += 384) sx[k] = xb[k];
    __syncthreads();
    const int t = threadIdx.x;
    unsigned short* ob = h1p + (size_t)b * H1_IMG;
    // zero M-pad rows 19,20: elems [5776, 6384) = 304 dwords
    if (t < 304) ((unsigned int*)(ob + 5776))[t] = 0u;
    if (t >= 361) return;
    const int oy = t / 19, ox = t % 19;
    float acc[10];
#pragma unroll
    for (int o = 0; o < 10; ++o) acc[o] = b1[o];
#pragma unroll 1
    for (int i = 0; i < 10; ++i) {
        float r[10];
#pragma unroll
        for (int j = 0; j < 10; ++j) r[j] = sx[(oy + i) * 28 + ox + j];
        const float* wp = w1 + i * 10;   // w1[o][i][j] = wp[o*100 + j]
#pragma unroll
        for (int j = 0; j < 10; ++j) {
#pragma unroll
            for (int o = 0; o < 10; ++o)
                acc[o] += r[j] * wp[o * 100 + j];
        }
    }
    unsigned short v[16];
#pragma unroll
    for (int o = 0; o < 10; ++o) v[o] = f2bf(fmaxf(acc[o], 0.f));
#pragma unroll
    for (int o = 10; o < 16; ++o) v[o] = 0;
    unsigned short* wp_ = ob + oy * H1_ROW + ox * 16;   // 16B aligned
    *(s16x8*)(wp_)     = *(const s16x8*)(v);
    *(s16x8*)(wp_ + 8) = *(const s16x8*)(v + 8);
}

// ---------------- conv2 MFMA: h1p bf16 -> relu -> h2 fp32 NCHW -------------
// 4 images/block (4 waves, 1 wave per image). Per wave: 7 M-tiles x 2 N-tiles.
#define C2B_IMGS 4
__global__ __launch_bounds__(256) void conv2_mfma_k(const unsigned short* __restrict__ h1p,
                                                    const unsigned short* __restrict__ wbuf,
                                                    const float* __restrict__ b2,
                                                    float* __restrict__ h2) {
    __shared__ __align__(16) unsigned short simg[C2B_IMGS * H1_IMG];  // 51072 B
    const int tid = threadIdx.x;
    const int b0 = blockIdx.x * C2B_IMGS;
    {
        const unsigned int* src = (const unsigned int*)(h1p + (size_t)b0 * H1_IMG);
        unsigned int* dst = (unsigned int*)simg;
        for (int k = tid; k < C2B_IMGS * H1_IMG / 2; k += 256) dst[k] = src[k];
    }
    __syncthreads();
    const int wave = tid >> 6, lane = tid & 63;
    const unsigned short* sb = simg + wave * H1_IMG;
    const int quad = lane >> 4, lm = lane & 15;
    int abase[7];
#pragma unroll
    for (int mt = 0; mt < 7; ++mt) {
        int m = mt * 16 + lm;
        int y = m / 10, xx = m - 10 * y;
        abase[mt] = y * H1_ROW + xx * 16 + quad * 8;
    }
    f32x4 acc[7][2] = {};
#pragma unroll 1
    for (int i = 0; i < 10; ++i) {
        const unsigned short* sbi = sb + i * H1_ROW;
        const unsigned short* wbi = wbuf + i * 5120 + lane * 8;
#pragma unroll 1
        for (int ck = 0; ck < 5; ++ck) {
            s16x8 wf0 = *(const s16x8*)(wbi + (ck * 2 + 0) * 512);
            s16x8 wf1 = *(const s16x8*)(wbi + (ck * 2 + 1) * 512);
            s16x8 af[7];
#pragma unroll
            for (int mt = 0; mt < 7; ++mt)
                af[mt] = *(const s16x8*)(sbi + abase[mt] + ck * 32);
#pragma unroll
            for (int mt = 0; mt < 7; ++mt) {
                acc[mt][0] = __builtin_amdgcn_mfma_f32_16x16x32_bf16(af[mt], wf0, acc[mt][0], 0, 0, 0);
                acc[mt][1] = __builtin_amdgcn_mfma_f32_16x16x32_bf16(af[mt], wf1, acc[mt][1], 0, 0, 0);
            }
        }
    }
    // D layout: col(n=o) = lane&15, row(m=pos) = quad*4 + reg
    float* outb = h2 + (size_t)(b0 + wave) * 2000;
#pragma unroll
    for (int nt = 0; nt < 2; ++nt) {
        int o = nt * 16 + lm;
        if (o >= 20) continue;
        float bias = b2[o];
        float* oo = outb + o * 100;
#pragma unroll
        for (int mt = 0; mt < 7; ++mt) {
#pragma unroll
            for (int r = 0; r < 4; ++r) {
                int pos = mt * 16 + quad * 4 + r;
                if (pos < 100) oo[pos] = fmaxf(acc[mt][nt][r] + bias, 0.f);
            }
        }
    }
}

// -------- conv3 + fc fused: [B,20,10,10] -> relu -> [B,720] @ wf^T + bf -----
__global__ __launch_bounds__(C3_THREADS) void conv3fc_k(const float* __restrict__ h2,
                                                        const float* __restrict__ w3,
                                                        const float* __restrict__ b3,
                                                        const float* __restrict__ wf,
                                                        const float* __restrict__ bf,
                                                        float* __restrict__ out, int B) {
    __shared__ float sin_[C3_IMGS * 2000];        // 48 KB
    __shared__ float spart[C3_IMGS * 36 * 10];    // 8.6 KB  fc partials
    const int b0 = blockIdx.x * C3_IMGS;
    const int nimg = min(C3_IMGS, B - b0);
    const int tot = nimg * 2000;
    const float* src = h2 + (size_t)b0 * 2000;
    for (int k = threadIdx.x; k < tot; k += C3_THREADS) sin_[k] = src[k];
    __syncthreads();
    const int t = threadIdx.x;
    const int ii = t / 36, pos = t % 36;
    if (ii < nimg && t < C3_IMGS * 36) {
        const int oy = pos / 6, ox = pos % 6;
        const float* sb = sin_ + ii * 2000;
        float acc[20];
#pragma unroll
        for (int o = 0; o < 20; ++o) acc[o] = b3[o];
#pragma unroll 1
        for (int c = 0; c < 20; ++c) {
#pragma unroll 1
            for (int i = 0; i < 5; ++i) {
                float r[5];
#pragma unroll
                for (int j = 0; j < 5; ++j)
                    r[j] = sb[c * 100 + (oy + i) * 10 + ox + j];
                const float* wp = w3 + c * 25 + i * 5; // w3[o][c][i][j]=wp[o*500+j]
#pragma unroll
                for (int j = 0; j < 5; ++j) {
#pragma unroll
                    for (int o = 0; o < 20; ++o)
                        acc[o] += r[j] * wp[o * 500 + j];
                }
            }
        }
        float part[10];
#pragma unroll
        for (int n = 0; n < 10; ++n) part[n] = 0.f;
#pragma unroll 1
        for (int o = 0; o < 20; ++o) {
            const float v = fmaxf(acc[o], 0.f);
            const float* wfp = wf + o * 36 + pos;   // wf[n][k]: stride 720 per n
#pragma unroll
            for (int n = 0; n < 10; ++n) part[n] += v * wfp[n * 720];
        }
        float* pp = spart + (ii * 36 + pos) * 10;
#pragma unroll
        for (int n = 0; n < 10; ++n) pp[n] = part[n];
    }
    __syncthreads();
    if (t < nimg * 10) {
        const int fi = t / 10, n = t % 10;
        float s = bf[n];
        const float* pp = spart + fi * 360 + n;
#pragma unroll 4
        for (int p = 0; p < 36; ++p) s += pp[p * 10];
        out[(b0 + fi) * 10 + n] = s;
    }
}

extern "C" void kernel_launch(void* const* d_in, const int* in_sizes, int n_in,
                              void* d_out, int out_size, void* d_ws, size_t ws_size,
                              hipStream_t stream) {
    (void)n_in; (void)out_size; (void)ws_size;
    const float* x  = (const float*)d_in[0];
    const float* w1 = (const float*)d_in[1];
    const float* b1 = (const float*)d_in[2];
    const float* w2 = (const float*)d_in[3];
    const float* b2 = (const float*)d_in[4];
    const float* w3 = (const float*)d_in[5];
    const float* b3 = (const float*)d_in[6];
    const float* wf = (const float*)d_in[7];
    const float* bf = (const float*)d_in[8];
    float* out = (float*)d_out;

    const int B = in_sizes[0] / 784;                       // 4096

    unsigned short* wbuf = (unsigned short*)d_ws;          // 51200 elems (100 KB)
    unsigned short* h1p  = wbuf + 51200;                   // B*6384 bf16 = 52.3 MB
    float* h2 = (float*)(h1p + (size_t)B * H1_IMG);        // B*2000 fp32 = 32.8 MB

    wprep_k<<<200, 256, 0, stream>>>(w2, wbuf);
    conv1_k<<<B, 384, 0, stream>>>(x, w1, b1, h1p);
    conv2_mfma_k<<<B / C2B_IMGS, 256, 0, stream>>>(h1p, wbuf, b2, h2);
    conv3fc_k<<<(B + C3_IMGS - 1) / C3_IMGS, C3_THREADS, 0, stream>>>(h2, w3, b3, wf, bf, out, B);
}

// Round 3
// 212.474 us; speedup vs baseline: 3.7882x; 1.6586x over previous
//
#include <hip/hip_runtime.h>

// LeNet-5 forward. conv2 + conv3 + fc fused in one kernel, both convs on
// bf16 MFMA (16x16x32); conv1 fp32 VALU.
//
// Layout trick (both convs): store activations NHWC with C padded so each
// im2col K-slice for a fixed kernel row is contiguous & 16B-aligned ->
// MFMA A-fragments are single ds_read_b128s.
//   h1: bf16 [y][x][c16],  row 304 elems, 21 rows (2 zero M-pad rows).
//   h2: bf16 [pos][c32] in LDS only (never touches HBM).
// Weights pre-packed into exact B-fragment order by wprep_k.

typedef short s16x8 __attribute__((ext_vector_type(8)));   // 8 bf16 (4 VGPRs)
typedef float f32x4 __attribute__((ext_vector_type(4)));

#define H1_ROW 304            // 19*16
#define H1_IMG 6384           // 21*304 elems (12768 B)

static __device__ __forceinline__ unsigned short f2bf(float f) {
    union { float f; unsigned int u; } v; v.f = f;
    unsigned int u = v.u;
    unsigned int r = (u + 0x7fffu + ((u >> 16) & 1u)) >> 16;   // RNE
    return (unsigned short)r;
}

// ---- weight prep: w2 -> wbuf[0:51200), w3 -> wbuf[51200:76800) ------------
// conv2: [i(10)][ck(5)][nt(2)][lane(64)][t(8)], k=ck*32+quad*8+t, j=k>>4,c=k&15
// conv3: [i(5)][ck(5)][nt(2)][lane(64)][t(8)],  k=ck*32+quad*8+t, j=k>>5,c=k&31
__global__ __launch_bounds__(256) void wprep_k(const float* __restrict__ w2,
                                               const float* __restrict__ w3,
                                               unsigned short* __restrict__ wbuf) {
    int e = blockIdx.x * 256 + threadIdx.x;
    if (e >= 76800) return;
    if (e < 51200) {
        int t = e & 7, lane = (e >> 3) & 63, nt = (e >> 9) & 1, ck = (e >> 10) % 5, i = e / 5120;
        int k = ck * 32 + (lane >> 4) * 8 + t;
        int o = nt * 16 + (lane & 15);
        int j = k >> 4, c = k & 15;
        float val = (c < 10 && o < 20) ? w2[o * 1000 + c * 100 + i * 10 + j] : 0.f;
        wbuf[e] = f2bf(val);
    } else {
        int e2 = e - 51200;
        int t = e2 & 7, lane = (e2 >> 3) & 63, nt = (e2 >> 9) & 1, ck = (e2 >> 10) % 5, i = e2 / 5120;
        int k = ck * 32 + (lane >> 4) * 8 + t;
        int o = nt * 16 + (lane & 15);
        int j = k >> 5, c = k & 31;
        float val = (c < 20 && o < 20) ? w3[o * 500 + c * 25 + i * 5 + j] : 0.f;
        wbuf[e] = f2bf(val);
    }
}

// ---------------- conv1: [B,1,28,28] -> relu -> h1p bf16 NHWC-C16 ----------
__global__ __launch_bounds__(384) void conv1_k(const float* __restrict__ x,
                                               const float* __restrict__ w1,
                                               const float* __restrict__ b1,
                                               unsigned short* __restrict__ h1p) {
    __shared__ float sx[784];
    const int b = blockIdx.x;
    const float* xb = x + b * 784;
    for (int k = threadIdx.x; k < 784; k += 384) sx[k] = xb[k];
    __syncthreads();
    const int t = threadIdx.x;
    unsigned short* ob = h1p + (size_t)b * H1_IMG;
    if (t < 304) ((unsigned int*)(ob + 5776))[t] = 0u;   // zero M-pad rows 19,20
    if (t >= 361) return;
    const int oy = t / 19, ox = t % 19;
    float acc[10];
#pragma unroll
    for (int o = 0; o < 10; ++o) acc[o] = b1[o];
#pragma unroll 1
    for (int i = 0; i < 10; ++i) {
        float r[10];
#pragma unroll
        for (int j = 0; j < 10; ++j) r[j] = sx[(oy + i) * 28 + ox + j];
        const float* wp = w1 + i * 10;
#pragma unroll
        for (int j = 0; j < 10; ++j) {
#pragma unroll
            for (int o = 0; o < 10; ++o)
                acc[o] += r[j] * wp[o * 100 + j];
        }
    }
    unsigned short v[16];
#pragma unroll
    for (int o = 0; o < 10; ++o) v[o] = f2bf(fmaxf(acc[o], 0.f));
#pragma unroll
    for (int o = 10; o < 16; ++o) v[o] = 0;
    unsigned short* wp_ = ob + oy * H1_ROW + ox * 16;
    *(s16x8*)(wp_)     = *(const s16x8*)(v);
    *(s16x8*)(wp_ + 8) = *(const s16x8*)(v + 8);
}

// ------------- fused conv2 (MFMA) + conv3 (MFMA) + fc (VALU) ----------------
// 4 images/block (1 wave per image). LDS phases:
//   phase1: simg[4*6384 bf16]  (51072 B)        -- h1 tiles
//   phase2: h2s [4*3200 bf16]  (25600 B, same base) + wfT[7200 f32] (28800 B)
__global__ __launch_bounds__(256) void conv23fc_k(const unsigned short* __restrict__ h1p,
                                                  const unsigned short* __restrict__ wbuf2,
                                                  const unsigned short* __restrict__ wbuf3,
                                                  const float* __restrict__ b2,
                                                  const float* __restrict__ b3,
                                                  const float* __restrict__ wf,
                                                  const float* __restrict__ bf,
                                                  float* __restrict__ out) {
    __shared__ __align__(16) unsigned char smem[54400];
    unsigned short* simg = (unsigned short*)smem;           // phase 1
    unsigned short* h2s  = (unsigned short*)smem;           // phase 2 (reuse)
    float*          wfT  = (float*)(smem + 25600);          // phase 2

    const int tid = threadIdx.x;
    const int b0 = blockIdx.x * 4;
    {
        const unsigned int* src = (const unsigned int*)(h1p + (size_t)b0 * H1_IMG);
        unsigned int* dst = (unsigned int*)simg;
        for (int k = tid; k < 4 * H1_IMG / 2; k += 256) dst[k] = src[k];
    }
    __syncthreads();

    const int wave = tid >> 6, lane = tid & 63;
    const int quad = lane >> 4, lm = lane & 15;

    // ---------------- conv2 MFMA: M=112(100), N=32(20), K=1600 -------------
    const unsigned short* sb = simg + wave * H1_IMG;
    int abase[7];
#pragma unroll
    for (int mt = 0; mt < 7; ++mt) {
        int m = mt * 16 + lm;
        int y = m / 10, xx = m - 10 * y;
        abase[mt] = y * H1_ROW + xx * 16 + quad * 8;
    }
    f32x4 acc[7][2] = {};
#pragma unroll 1
    for (int i = 0; i < 10; ++i) {
        const unsigned short* sbi = sb + i * H1_ROW;
        const unsigned short* wbi = wbuf2 + i * 5120 + lane * 8;
#pragma unroll 1
        for (int ck = 0; ck < 5; ++ck) {
            s16x8 wf0 = *(const s16x8*)(wbi + (ck * 2 + 0) * 512);
            s16x8 wf1 = *(const s16x8*)(wbi + (ck * 2 + 1) * 512);
            s16x8 af[7];
#pragma unroll
            for (int mt = 0; mt < 7; ++mt)
                af[mt] = *(const s16x8*)(sbi + abase[mt] + ck * 32);
#pragma unroll
            for (int mt = 0; mt < 7; ++mt) {
                acc[mt][0] = __builtin_amdgcn_mfma_f32_16x16x32_bf16(af[mt], wf0, acc[mt][0], 0, 0, 0);
                acc[mt][1] = __builtin_amdgcn_mfma_f32_16x16x32_bf16(af[mt], wf1, acc[mt][1], 0, 0, 0);
            }
        }
    }
    __syncthreads();   // all waves done reading simg; safe to overwrite

    // stage wf transposed: wfT[k*10+n] = wf[n*720+k]  (coalesced global read)
    for (int e = tid; e < 7200; e += 256) {
        int n = e / 720, k = e - n * 720;
        wfT[k * 10 + n] = wf[e];
    }
    // scatter conv2 result into h2s NHWC-C32 (zeros for pad channels)
    {
        unsigned short* hb = h2s + wave * 3200;
#pragma unroll
        for (int nt = 0; nt < 2; ++nt) {
            int o = nt * 16 + lm;
            float bias = (o < 20) ? b2[o] : 0.f;
#pragma unroll
            for (int mt = 0; mt < 7; ++mt) {
#pragma unroll
                for (int r = 0; r < 4; ++r) {
                    int pos = mt * 16 + quad * 4 + r;
                    if (pos < 100)
                        hb[pos * 32 + o] = (o < 20) ? f2bf(fmaxf(acc[mt][nt][r] + bias, 0.f))
                                                    : (unsigned short)0;
                }
            }
        }
    }
    __syncthreads();

    // ---------------- conv3 MFMA: M=48(36), N=32(20), K=800 ----------------
    const unsigned short* hb2 = h2s + wave * 3200;
    int abase3[3];
#pragma unroll
    for (int mt = 0; mt < 3; ++mt) {
        int m = mt * 16 + lm;
        if (m < 36) {
            int oy = m / 6, ox = m - 6 * oy;
            abase3[mt] = oy * 320 + ox * 32 + quad * 8;
        } else {
            abase3[mt] = quad * 8;   // pad row: read anything valid, discard
        }
    }
    f32x4 acc3[3][2] = {};
#pragma unroll 1
    for (int i = 0; i < 5; ++i) {
        const unsigned short* sbi = hb2 + i * 320;
        const unsigned short* wbi = wbuf3 + i * 5120 + lane * 8;
#pragma unroll 1
        for (int ck = 0; ck < 5; ++ck) {
            s16x8 w0 = *(const s16x8*)(wbi + (ck * 2 + 0) * 512);
            s16x8 w1 = *(const s16x8*)(wbi + (ck * 2 + 1) * 512);
            s16x8 af[3];
#pragma unroll
            for (int mt = 0; mt < 3; ++mt)
                af[mt] = *(const s16x8*)(sbi + abase3[mt] + ck * 32);
#pragma unroll
            for (int mt = 0; mt < 3; ++mt) {
                acc3[mt][0] = __builtin_amdgcn_mfma_f32_16x16x32_bf16(af[mt], w0, acc3[mt][0], 0, 0, 0);
                acc3[mt][1] = __builtin_amdgcn_mfma_f32_16x16x32_bf16(af[mt], w1, acc3[mt][1], 0, 0, 0);
            }
        }
    }

    // ---------------- fc: per-lane partials over real (o,pos), wave-reduce --
    float part[10];
#pragma unroll
    for (int n = 0; n < 10; ++n) part[n] = 0.f;
#pragma unroll
    for (int nt = 0; nt < 2; ++nt) {
        int o = nt * 16 + lm;
        if (o < 20) {
            float b3v = b3[o];
#pragma unroll
            for (int mt = 0; mt < 3; ++mt) {
#pragma unroll
                for (int r = 0; r < 4; ++r) {
                    int pos = mt * 16 + quad * 4 + r;
                    if (pos < 36) {
                        float v = fmaxf(acc3[mt][nt][r] + b3v, 0.f);
                        const float* wp = wfT + (o * 36 + pos) * 10;
#pragma unroll
                        for (int n = 0; n < 10; ++n) part[n] += v * wp[n];
                    }
                }
            }
        }
    }
#pragma unroll
    for (int n = 0; n < 10; ++n) {
#pragma unroll
        for (int off = 32; off >= 1; off >>= 1)
            part[n] += __shfl_xor(part[n], off, 64);
    }
    if (lane == 0) {
        float* op = out + (size_t)(b0 + wave) * 10;
#pragma unroll
        for (int n = 0; n < 10; ++n) op[n] = part[n] + bf[n];
    }
}

extern "C" void kernel_launch(void* const* d_in, const int* in_sizes, int n_in,
                              void* d_out, int out_size, void* d_ws, size_t ws_size,
                              hipStream_t stream) {
    (void)n_in; (void)out_size; (void)ws_size;
    const float* x  = (const float*)d_in[0];
    const float* w1 = (const float*)d_in[1];
    const float* b1 = (const float*)d_in[2];
    const float* w2 = (const float*)d_in[3];
    const float* b2 = (const float*)d_in[4];
    const float* w3 = (const float*)d_in[5];
    const float* b3 = (const float*)d_in[6];
    const float* wf = (const float*)d_in[7];
    const float* bf = (const float*)d_in[8];
    float* out = (float*)d_out;

    const int B = in_sizes[0] / 784;                       // 4096

    unsigned short* wbuf = (unsigned short*)d_ws;          // 76800 elems (150 KB)
    unsigned short* h1p  = wbuf + 76800;                   // B*6384 bf16 = 52.3 MB

    wprep_k<<<300, 256, 0, stream>>>(w2, w3, wbuf);
    conv1_k<<<B, 384, 0, stream>>>(x, w1, b1, h1p);
    conv23fc_k<<<B / 4, 256, 0, stream>>>(h1p, wbuf, wbuf + 51200, b2, b3, wf, bf, out);
}

// Round 4
// 198.497 us; speedup vs baseline: 4.0549x; 1.0704x over previous
//
#include <hip/hip_runtime.h>

// LeNet-5 forward, fully fused: conv1 (fp32 VALU) + conv2 (bf16 MFMA) +
// conv3 (bf16 MFMA) + fc (fp32 VALU) in ONE kernel; h1/h2 live only in LDS.
//
// Padding trick: all K-dim zero-padding lives in the PRE-PACKED WEIGHTS
// (wprep_k). Activations use exact-C NHWC, so the im2col K-slice for a fixed
// kernel row (k = j*C + c) is naturally contiguous; k beyond the real range
// reads finite neighbor values that hit zero weights. Only LDS pad regions
// that could hold stale garbage (possible NaN bit patterns) are zeroed.
//
//   h1: bf16 [img][y(19)][x(19)][c(10..11 pad-slot)]  row=228, img=4332 (+16 tail)
//   h2: bf16 [img][pos(100)][c(20)] img stride 2048 (pad [2000,2048) zeroed)
//   conv2: K per i-row = 120 -> 128 (4 chunks of 32), frags = 2x ds_read_b64
//   conv3: K per i-row = 100 -> 128 (4 chunks of 32), frags = 2x ds_read_b64

typedef short s16x4 __attribute__((ext_vector_type(4)));   // 4 bf16 (8 B)
typedef short s16x8 __attribute__((ext_vector_type(8)));   // 8 bf16 (4 VGPRs)
typedef float f32x4 __attribute__((ext_vector_type(4)));

#define ROW1 228            // 19*12
#define IMG1 4332           // 19*228
#define H1_ELEMS (4*IMG1 + 16)          // 17344 bf16 = 34688 B
#define SM_X_BYTES   12544              // 4*784 fp32
#define SM_H1_OFF    12544
#define SM_H2S_BYTES 16384              // 4*2048 bf16
#define SM_WFT_OFF   16384
#define SM_BYTES     48064              // 16384 + 720*11*4

static __device__ __forceinline__ unsigned short f2bf(float f) {
    union { float f; unsigned int u; } v; v.f = f;
    unsigned int u = v.u;
    unsigned int r = (u + 0x7fffu + ((u >> 16) & 1u)) >> 16;   // RNE
    return (unsigned short)r;
}

// ---- weight prep: w2 -> wbuf[0:40960), w3 -> wbuf[40960:61440) ------------
// conv2: [i(10)][ck(4)][nt(2)][lane(64)][t(8)], k=ck*32+quad*8+t, j=k/12, c=k%12
// conv3: [i(5)][ck(4)][nt(2)][lane(64)][t(8)],  k=ck*32+quad*8+t, j=k/20, c=k%20
__global__ __launch_bounds__(256) void wprep_k(const float* __restrict__ w2,
                                               const float* __restrict__ w3,
                                               unsigned short* __restrict__ wbuf) {
    int e = blockIdx.x * 256 + threadIdx.x;
    if (e >= 61440) return;
    if (e < 40960) {
        int t = e & 7, lane = (e >> 3) & 63, nt = (e >> 9) & 1;
        int ck = (e >> 10) & 3, i = e >> 12;
        int k = ck * 32 + ((lane >> 4) & 3) * 8 + t;          // 0..127
        int o = nt * 16 + (lane & 15);
        int j = k / 12, c = k % 12;
        float val = (j < 10 && c < 10 && o < 20) ? w2[o * 1000 + c * 100 + i * 10 + j] : 0.f;
        wbuf[e] = f2bf(val);
    } else {
        int e2 = e - 40960;
        int t = e2 & 7, lane = (e2 >> 3) & 63, nt = (e2 >> 9) & 1;
        int ck = (e2 >> 10) & 3, i = e2 >> 12;
        int k = ck * 32 + ((lane >> 4) & 3) * 8 + t;          // 0..127
        int o = nt * 16 + (lane & 15);
        int j = k / 20, c = k % 20;
        float val = (j < 5 && o < 20) ? w3[o * 500 + c * 25 + i * 5 + j] : 0.f;
        wbuf[e] = f2bf(val);
    }
}

// --------------------------- the fused kernel ------------------------------
// 4 images/block, 256 threads (4 waves; 1 wave per image for the MFMA parts).
__global__ __launch_bounds__(256) void fused_k(const float* __restrict__ x,
                                               const float* __restrict__ w1,
                                               const float* __restrict__ b1,
                                               const unsigned short* __restrict__ wbuf2,
                                               const unsigned short* __restrict__ wbuf3,
                                               const float* __restrict__ b2,
                                               const float* __restrict__ b3,
                                               const float* __restrict__ wf,
                                               const float* __restrict__ bf,
                                               float* __restrict__ out) {
    __shared__ __align__(16) unsigned char smem[SM_BYTES];
    float*          sx  = (float*)smem;                       // phase 0/1
    unsigned short* h1  = (unsigned short*)(smem + SM_H1_OFF);// phase 1/2
    unsigned short* h2s = (unsigned short*)smem;              // phase 3
    float*          wfT = (float*)(smem + SM_WFT_OFF);        // phase 3

    const int tid = threadIdx.x;
    const int b0 = blockIdx.x * 4;

    // ---- stage x (4 x 784 fp32, float4-coalesced) ----
    {
        const float4* src = (const float4*)(x + (size_t)b0 * 784);
        float4* dst = (float4*)sx;
        for (int k = tid; k < 784; k += 256) dst[k] = src[k];
    }
    __syncthreads();

    // ---- conv1 (fp32 VALU): 4*361 = 1444 output positions ----
    if (tid < 16) h1[4 * IMG1 + tid] = 0;     // zero h1 tail pad (NaN safety)
    for (int task = tid; task < 1444; task += 256) {
        int img = task / 361;
        int pos = task - img * 361;
        int oy = pos / 19, ox = pos - oy * 19;
        const float* sb = sx + img * 784;
        float acc[10];
#pragma unroll
        for (int o = 0; o < 10; ++o) acc[o] = b1[o];
#pragma unroll 1
        for (int i = 0; i < 10; ++i) {
            float r[10];
#pragma unroll
            for (int j = 0; j < 10; ++j) r[j] = sb[(oy + i) * 28 + ox + j];
            const float* wp = w1 + i * 10;    // w1[o][i][j] = wp[o*100 + j]
#pragma unroll
            for (int j = 0; j < 10; ++j) {
#pragma unroll
                for (int o = 0; o < 10; ++o)
                    acc[o] += r[j] * wp[o * 100 + j];
            }
        }
        unsigned short v[12];
#pragma unroll
        for (int o = 0; o < 10; ++o) v[o] = f2bf(fmaxf(acc[o], 0.f));
        v[10] = 0; v[11] = 0;
        unsigned short* dst = h1 + img * IMG1 + oy * ROW1 + ox * 12;  // 8B-aligned
        s16x4* d4 = (s16x4*)dst;
        d4[0] = (s16x4){ (short)v[0], (short)v[1], (short)v[2],  (short)v[3]  };
        d4[1] = (s16x4){ (short)v[4], (short)v[5], (short)v[6],  (short)v[7]  };
        d4[2] = (s16x4){ (short)v[8], (short)v[9], (short)v[10], (short)v[11] };
    }
    __syncthreads();

    const int wave = tid >> 6, lane = tid & 63;
    const int quad = lane >> 4, lm = lane & 15;

    // ---- conv2 MFMA: M=112(100), N=32(20), K=1280 (real 1000) ----
    const unsigned short* sb1 = h1 + wave * IMG1;
    int abase[7];
#pragma unroll
    for (int mt = 0; mt < 7; ++mt) {
        int m = mt * 16 + lm;
        if (m > 99) m = 99;                   // pad rows: duplicate, discard later
        int y = m / 10, xx = m - 10 * y;
        abase[mt] = y * ROW1 + xx * 12 + quad * 8;
    }
    f32x4 acc[7][2] = {};
#pragma unroll 1
    for (int i = 0; i < 10; ++i) {
        const unsigned short* sbi = sb1 + i * ROW1;
        const unsigned short* wbi = wbuf2 + i * 4096 + lane * 8;
#pragma unroll
        for (int ck = 0; ck < 4; ++ck) {
            s16x8 wf0 = *(const s16x8*)(wbi + (ck * 2 + 0) * 512);
            s16x8 wf1 = *(const s16x8*)(wbi + (ck * 2 + 1) * 512);
            s16x8 af[7];
#pragma unroll
            for (int mt = 0; mt < 7; ++mt) {
                const unsigned short* p = sbi + abase[mt] + ck * 32;
                s16x4 lo = *(const s16x4*)(p);
                s16x4 hi = *(const s16x4*)(p + 4);
                af[mt] = __builtin_shufflevector(lo, hi, 0, 1, 2, 3, 4, 5, 6, 7);
            }
#pragma unroll
            for (int mt = 0; mt < 7; ++mt) {
                acc[mt][0] = __builtin_amdgcn_mfma_f32_16x16x32_bf16(af[mt], wf0, acc[mt][0], 0, 0, 0);
                acc[mt][1] = __builtin_amdgcn_mfma_f32_16x16x32_bf16(af[mt], wf1, acc[mt][1], 0, 0, 0);
            }
        }
    }
    __syncthreads();   // h1 dead; safe to overwrite with h2s/wfT

    // ---- stage wfT (row-padded to 11 for bank spread) + zero h2s pads ----
    for (int e = tid; e < 7200; e += 256) {
        int n = e / 720, k = e - n * 720;
        wfT[k * 11 + n] = wf[e];
    }
    if (tid < 192) {                           // zero h2s pad [2000,2048) x 4 imgs
        int img = tid / 48, e = tid - img * 48;
        h2s[img * 2048 + 2000 + e] = 0;
    }
    // ---- scatter conv2 -> h2s NHWC-C20 (bf16) ----
    {
        unsigned short* hb = h2s + wave * 2048;
#pragma unroll
        for (int nt = 0; nt < 2; ++nt) {
            int o = nt * 16 + lm;
            if (o < 20) {
                float bias = b2[o];
#pragma unroll
                for (int mt = 0; mt < 7; ++mt) {
#pragma unroll
                    for (int r = 0; r < 4; ++r) {
                        int pos = mt * 16 + quad * 4 + r;
                        if (pos < 100)
                            hb[pos * 20 + o] = f2bf(fmaxf(acc[mt][nt][r] + bias, 0.f));
                    }
                }
            }
        }
    }
    __syncthreads();

    // ---- conv3 MFMA: M=48(36), N=32(20), K=640 (real 500) ----
    const unsigned short* hb2 = h2s + wave * 2048;
    int abase3[3];
#pragma unroll
    for (int mt = 0; mt < 3; ++mt) {
        int m = mt * 16 + lm;
        if (m > 35) m = 35;
        int oy = m / 6, ox = m - 6 * oy;
        abase3[mt] = oy * 200 + ox * 20 + quad * 8;
    }
    f32x4 acc3[3][2] = {};
#pragma unroll 1
    for (int i = 0; i < 5; ++i) {
        const unsigned short* sbi = hb2 + i * 200;
        const unsigned short* wbi = wbuf3 + i * 4096 + lane * 8;
#pragma unroll
        for (int ck = 0; ck < 4; ++ck) {
            s16x8 w0 = *(const s16x8*)(wbi + (ck * 2 + 0) * 512);
            s16x8 w1 = *(const s16x8*)(wbi + (ck * 2 + 1) * 512);
            s16x8 af[3];
#pragma unroll
            for (int mt = 0; mt < 3; ++mt) {
                const unsigned short* p = sbi + abase3[mt] + ck * 32;
                s16x4 lo = *(const s16x4*)(p);
                s16x4 hi = *(const s16x4*)(p + 4);
                af[mt] = __builtin_shufflevector(lo, hi, 0, 1, 2, 3, 4, 5, 6, 7);
            }
#pragma unroll
            for (int mt = 0; mt < 3; ++mt) {
                acc3[mt][0] = __builtin_amdgcn_mfma_f32_16x16x32_bf16(af[mt], w0, acc3[mt][0], 0, 0, 0);
                acc3[mt][1] = __builtin_amdgcn_mfma_f32_16x16x32_bf16(af[mt], w1, acc3[mt][1], 0, 0, 0);
            }
        }
    }

    // ---- fc (fp32): per-lane partials over real (o,pos), wave-reduce ----
    float part[10];
#pragma unroll
    for (int n = 0; n < 10; ++n) part[n] = 0.f;
#pragma unroll
    for (int nt = 0; nt < 2; ++nt) {
        int o = nt * 16 + lm;
        if (o < 20) {
            float b3v = b3[o];
#pragma unroll
            for (int mt = 0; mt < 3; ++mt) {
#pragma unroll
                for (int r = 0; r < 4; ++r) {
                    int pos = mt * 16 + quad * 4 + r;
                    if (pos < 36) {
                        float v = fmaxf(acc3[mt][nt][r] + b3v, 0.f);
                        const float* wp = wfT + (o * 36 + pos) * 11;
#pragma unroll
                        for (int n = 0; n < 10; ++n) part[n] += v * wp[n];
                    }
                }
            }
        }
    }
#pragma unroll
    for (int n = 0; n < 10; ++n) {
#pragma unroll
        for (int off = 32; off >= 1; off >>= 1)
            part[n] += __shfl_xor(part[n], off, 64);
    }
    if (lane == 0) {
        float* op = out + (size_t)(b0 + wave) * 10;
#pragma unroll
        for (int n = 0; n < 10; ++n) op[n] = part[n] + bf[n];
    }
}

extern "C" void kernel_launch(void* const* d_in, const int* in_sizes, int n_in,
                              void* d_out, int out_size, void* d_ws, size_t ws_size,
                              hipStream_t stream) {
    (void)n_in; (void)out_size; (void)ws_size;
    const float* x  = (const float*)d_in[0];
    const float* w1 = (const float*)d_in[1];
    const float* b1 = (const float*)d_in[2];
    const float* w2 = (const float*)d_in[3];
    const float* b2 = (const float*)d_in[4];
    const float* w3 = (const float*)d_in[5];
    const float* b3 = (const float*)d_in[6];
    const float* wf = (const float*)d_in[7];
    const float* bf = (const float*)d_in[8];
    float* out = (float*)d_out;

    const int B = in_sizes[0] / 784;                       // 4096

    unsigned short* wbuf = (unsigned short*)d_ws;          // 61440 bf16 = 120 KB

    wprep_k<<<240, 256, 0, stream>>>(w2, w3, wbuf);
    fused_k<<<B / 4, 256, 0, stream>>>(x, w1, b1, wbuf, wbuf + 40960,
                                       b2, b3, wf, bf, out);
}

// Round 5
// 167.593 us; speedup vs baseline: 4.8026x; 1.1844x over previous
//
#include <hip/hip_runtime.h>

// LeNet-5 forward, fully fused, ONE WAVE PER IMAGE (64-thread blocks).
// No inter-wave barriers: each image is an independent pipeline
// conv1(fp32 VALU) -> conv2(bf16 MFMA) -> conv3(bf16 MFMA) -> fc(fp32 VALU).
// ~12 blocks/CU (12.8 KB LDS each) overlap their phases across pipes.
//
// Activations NHWC with exact-C (pad lives in pre-packed weights):
//   h1: bf16 [y(19)][x(19)][c12]  row 228 elems, img 4332 (+20 zero tail)
//   h2: bf16 [pos(100)][c20]      2048 elems in LDS ([2000,2048) zeroed)
//   conv2: K/row = 120->128 (4 chunks), conv3: K/row = 100->128 (4 chunks)
// fc: h3 -> linear LDS buffer (720 f32), dot with GLOBAL wf (coalesced, L1).

typedef short s16x4 __attribute__((ext_vector_type(4)));
typedef short s16x8 __attribute__((ext_vector_type(8)));
typedef float f32x4 __attribute__((ext_vector_type(4)));

#define ROW1 228            // 19*12
#define IMG1 4332           // 19*228

static __device__ __forceinline__ unsigned short f2bf(float f) {
    union { float f; unsigned int u; } v; v.f = f;
    unsigned int u = v.u;
    unsigned int r = (u + 0x7fffu + ((u >> 16) & 1u)) >> 16;   // RNE
    return (unsigned short)r;
}

// ---- weight prep ----------------------------------------------------------
// wbuf ushort: [0,40960) conv2 B-frags, [40960,61440) conv3 B-frags,
//              [61440, 61440+2000) = w1p as 1000 fp32 (pair-friendly layout).
// conv2: [i(10)][ck(4)][nt(2)][lane(64)][t(8)], k=ck*32+quad*8+t, j=k/12, c=k%12
// conv3: [i(5)][ck(4)][nt(2)][lane(64)][t(8)],  k=ck*32+quad*8+t, j=k/20, c=k%20
// w1p[(i*10+j)*10 + o] = w1[o][i][j]  (consecutive o -> packed fp32 pairs)
__global__ __launch_bounds__(256) void wprep_k(const float* __restrict__ w2,
                                               const float* __restrict__ w3,
                                               const float* __restrict__ w1,
                                               unsigned short* __restrict__ wbuf) {
    int e = blockIdx.x * 256 + threadIdx.x;
    if (e < 40960) {
        int t = e & 7, lane = (e >> 3) & 63, nt = (e >> 9) & 1;
        int ck = (e >> 10) & 3, i = e >> 12;
        int k = ck * 32 + ((lane >> 4) & 3) * 8 + t;          // 0..127
        int o = nt * 16 + (lane & 15);
        int j = k / 12, c = k % 12;
        float val = (j < 10 && c < 10 && o < 20) ? w2[o * 1000 + c * 100 + i * 10 + j] : 0.f;
        wbuf[e] = f2bf(val);
    } else if (e < 61440) {
        int e2 = e - 40960;
        int t = e2 & 7, lane = (e2 >> 3) & 63, nt = (e2 >> 9) & 1;
        int ck = (e2 >> 10) & 3, i = e2 >> 12;
        int k = ck * 32 + ((lane >> 4) & 3) * 8 + t;          // 0..127
        int o = nt * 16 + (lane & 15);
        int j = k / 20, c = k % 20;
        float val = (j < 5 && o < 20) ? w3[o * 500 + c * 25 + i * 5 + j] : 0.f;
        wbuf[e] = f2bf(val);
    } else if (e < 62440) {
        int t = e - 61440;                 // t = (i*10+j)*10 + o
        int o = t % 10, ij = t / 10;
        int i = ij / 10, j = ij % 10;
        ((float*)(wbuf + 61440))[t] = w1[o * 100 + i * 10 + j];
    }
}

// --------------------------- the fused kernel ------------------------------
__global__ __launch_bounds__(64, 3) void fused_k(const float* __restrict__ x,
                                                 const float* __restrict__ w1p,
                                                 const float* __restrict__ b1,
                                                 const unsigned short* __restrict__ wbuf2,
                                                 const unsigned short* __restrict__ wbuf3,
                                                 const float* __restrict__ b2,
                                                 const float* __restrict__ b3,
                                                 const float* __restrict__ wf,
                                                 const float* __restrict__ bf,
                                                 float* __restrict__ out) {
    __shared__ __align__(16) unsigned char smem[12800];
    unsigned short* h1  = (unsigned short*)smem;              // [0, 8704)
    float*          sxf = (float*)(smem + 8704);              // x (3136 B)
    unsigned short* h2s = (unsigned short*)(smem + 8704);     // later (4096 B)
    float*          h3s = (float*)(smem + 8704);              // later (2880 B)

    const int lane = threadIdx.x;
    const int b = blockIdx.x;
    const int quad = lane >> 4, lm = lane & 15;

    // ---- stage x (784 fp32, float4) + zero h1 tail ----
    {
        const float4* src = (const float4*)(x + (size_t)b * 784);
        float4* dst = (float4*)sxf;
        for (int k = lane; k < 196; k += 64) dst[k] = src[k];
    }
    if (lane < 20) h1[IMG1 + lane] = 0;       // zero tail pad (NaN safety)
    __syncthreads();

    // ---- conv1 (fp32 VALU, paired for v_pk_fma_f32): 361 positions ----
    for (int it = 0; it < 6; ++it) {
        int pos = it * 64 + lane;
        if (pos < 361) {
            int oy = pos / 19, ox = pos - oy * 19;
            float2 acc2[5];
#pragma unroll
            for (int p = 0; p < 5; ++p) acc2[p] = make_float2(b1[2 * p], b1[2 * p + 1]);
#pragma unroll 1
            for (int i = 0; i < 10; ++i) {
                float r[10];
#pragma unroll
                for (int j = 0; j < 10; ++j) r[j] = sxf[(oy + i) * 28 + ox + j];
                const float* wbase = w1p + i * 100;
#pragma unroll
                for (int j = 0; j < 10; ++j) {
                    const float2* wp = (const float2*)(wbase + j * 10);
                    float rj = r[j];
#pragma unroll
                    for (int p = 0; p < 5; ++p) {
                        float2 w = wp[p];
                        acc2[p].x = fmaf(rj, w.x, acc2[p].x);
                        acc2[p].y = fmaf(rj, w.y, acc2[p].y);
                    }
                }
            }
            unsigned short v[12];
#pragma unroll
            for (int p = 0; p < 5; ++p) {
                v[2 * p]     = f2bf(fmaxf(acc2[p].x, 0.f));
                v[2 * p + 1] = f2bf(fmaxf(acc2[p].y, 0.f));
            }
            v[10] = 0; v[11] = 0;
            unsigned short* dst = h1 + oy * ROW1 + ox * 12;   // 8B-aligned
            s16x4* d4 = (s16x4*)dst;
            d4[0] = (s16x4){ (short)v[0], (short)v[1], (short)v[2],  (short)v[3]  };
            d4[1] = (s16x4){ (short)v[4], (short)v[5], (short)v[6],  (short)v[7]  };
            d4[2] = (s16x4){ (short)v[8], (short)v[9], (short)v[10], (short)v[11] };
        }
    }
    __syncthreads();

    // ---- conv2 MFMA: M=112(100), N=32(20), K=1280 (real 1000) ----
    int abase[7];
#pragma unroll
    for (int mt = 0; mt < 7; ++mt) {
        int m = mt * 16 + lm;
        if (m > 99) m = 99;                   // pad rows: duplicate, discard
        int y = m / 10, xx = m - 10 * y;
        abase[mt] = y * ROW1 + xx * 12 + quad * 8;
    }
    f32x4 acc[7][2] = {};
#pragma unroll 1
    for (int i = 0; i < 10; ++i) {
        const unsigned short* sbi = h1 + i * ROW1;
        const unsigned short* wbi = wbuf2 + i * 4096 + lane * 8;
#pragma unroll
        for (int ck = 0; ck < 4; ++ck) {
            s16x8 wf0 = *(const s16x8*)(wbi + (ck * 2 + 0) * 512);
            s16x8 wf1 = *(const s16x8*)(wbi + (ck * 2 + 1) * 512);
            s16x8 af[7];
#pragma unroll
            for (int mt = 0; mt < 7; ++mt) {
                const unsigned short* p = sbi + abase[mt] + ck * 32;
                s16x4 lo = *(const s16x4*)(p);
                s16x4 hi = *(const s16x4*)(p + 4);
                af[mt] = __builtin_shufflevector(lo, hi, 0, 1, 2, 3, 4, 5, 6, 7);
            }
#pragma unroll
            for (int mt = 0; mt < 7; ++mt) {
                acc[mt][0] = __builtin_amdgcn_mfma_f32_16x16x32_bf16(af[mt], wf0, acc[mt][0], 0, 0, 0);
                acc[mt][1] = __builtin_amdgcn_mfma_f32_16x16x32_bf16(af[mt], wf1, acc[mt][1], 0, 0, 0);
            }
        }
    }
    __syncthreads();   // x region dead; reuse as h2s

    // ---- scatter conv2 -> h2s NHWC-C20 (bf16), zero pad ----
    if (lane < 48) h2s[2000 + lane] = 0;
#pragma unroll
    for (int nt = 0; nt < 2; ++nt) {
        int o = nt * 16 + lm;
        if (o < 20) {
            float bias = b2[o];
#pragma unroll
            for (int mt = 0; mt < 7; ++mt) {
#pragma unroll
                for (int r = 0; r < 4; ++r) {
                    int pos = mt * 16 + quad * 4 + r;
                    if (pos < 100)
                        h2s[pos * 20 + o] = f2bf(fmaxf(acc[mt][nt][r] + bias, 0.f));
                }
            }
        }
    }
    __syncthreads();

    // ---- conv3 MFMA: M=48(36), N=32(20), K=640 (real 500) ----
    int abase3[3];
#pragma unroll
    for (int mt = 0; mt < 3; ++mt) {
        int m = mt * 16 + lm;
        if (m > 35) m = 35;
        int oy = m / 6, ox = m - 6 * oy;
        abase3[mt] = oy * 200 + ox * 20 + quad * 8;
    }
    f32x4 acc3[3][2] = {};
#pragma unroll 1
    for (int i = 0; i < 5; ++i) {
        const unsigned short* sbi = h2s + i * 200;
        const unsigned short* wbi = wbuf3 + i * 4096 + lane * 8;
#pragma unroll
        for (int ck = 0; ck < 4; ++ck) {
            s16x8 w0 = *(const s16x8*)(wbi + (ck * 2 + 0) * 512);
            s16x8 w1 = *(const s16x8*)(wbi + (ck * 2 + 1) * 512);
            s16x8 af[3];
#pragma unroll
            for (int mt = 0; mt < 3; ++mt) {
                const unsigned short* p = sbi + abase3[mt] + ck * 32;
                s16x4 lo = *(const s16x4*)(p);
                s16x4 hi = *(const s16x4*)(p + 4);
                af[mt] = __builtin_shufflevector(lo, hi, 0, 1, 2, 3, 4, 5, 6, 7);
            }
#pragma unroll
            for (int mt = 0; mt < 3; ++mt) {
                acc3[mt][0] = __builtin_amdgcn_mfma_f32_16x16x32_bf16(af[mt], w0, acc3[mt][0], 0, 0, 0);
                acc3[mt][1] = __builtin_amdgcn_mfma_f32_16x16x32_bf16(af[mt], w1, acc3[mt][1], 0, 0, 0);
            }
        }
    }
    __syncthreads();   // h2s reads done; reuse region as h3s

    // ---- conv3 epilogue -> linear h3s[o*36+pos] (fp32, relu) ----
#pragma unroll
    for (int nt = 0; nt < 2; ++nt) {
        int o = nt * 16 + lm;
        if (o < 20) {
            float b3v = b3[o];
#pragma unroll
            for (int mt = 0; mt < 3; ++mt) {
#pragma unroll
                for (int r = 0; r < 4; ++r) {
                    int pos = mt * 16 + quad * 4 + r;
                    if (pos < 36)
                        h3s[o * 36 + pos] = fmaxf(acc3[mt][nt][r] + b3v, 0.f);
                }
            }
        }
    }
    __syncthreads();

    // ---- fc: coalesced global wf, lane l handles k = l + 64s ----
    float part[10];
#pragma unroll
    for (int n = 0; n < 10; ++n) part[n] = 0.f;
#pragma unroll 1
    for (int s = 0; s < 12; ++s) {
        int k = s * 64 + lane;
        if (k < 720) {
            float v = h3s[k];
#pragma unroll
            for (int n = 0; n < 10; ++n)
                part[n] = fmaf(v, wf[n * 720 + k], part[n]);
        }
    }
#pragma unroll
    for (int n = 0; n < 10; ++n) {
#pragma unroll
        for (int off = 32; off >= 1; off >>= 1)
            part[n] += __shfl_xor(part[n], off, 64);
    }
    if (lane == 0) {
        float* op = out + (size_t)b * 10;
#pragma unroll
        for (int n = 0; n < 10; ++n) op[n] = part[n] + bf[n];
    }
}

extern "C" void kernel_launch(void* const* d_in, const int* in_sizes, int n_in,
                              void* d_out, int out_size, void* d_ws, size_t ws_size,
                              hipStream_t stream) {
    (void)n_in; (void)out_size; (void)ws_size;
    const float* x  = (const float*)d_in[0];
    const float* w1 = (const float*)d_in[1];
    const float* b1 = (const float*)d_in[2];
    const float* w2 = (const float*)d_in[3];
    const float* b2 = (const float*)d_in[4];
    const float* w3 = (const float*)d_in[5];
    const float* b3 = (const float*)d_in[6];
    const float* wf = (const float*)d_in[7];
    const float* bf = (const float*)d_in[8];
    float* out = (float*)d_out;

    const int B = in_sizes[0] / 784;                       // 4096

    unsigned short* wbuf = (unsigned short*)d_ws;          // ~127 KB
    const float* w1p = (const float*)(wbuf + 61440);

    wprep_k<<<244, 256, 0, stream>>>(w2, w3, w1, wbuf);
    fused_k<<<B, 64, 0, stream>>>(x, w1p, b1, wbuf, wbuf + 40960,
                                  b2, b3, wf, bf, out);
}